// Round 1
// baseline (909.255 us; speedup 1.0000x reference)
//
#include <hip/hip_runtime.h>
#include <hip/hip_bf16.h>
#include <math.h>

#define H 128
#define FEAT 9

// ---------------- Atom encoder: h[v] = sum_f emb[f, x[v,f], :] ----------------
__global__ __launch_bounds__(256) void k_atom(const int* __restrict__ x,
    const float* __restrict__ emb, float* __restrict__ h,
    int N, int Npad, int maxv) {
  int wid = (blockIdx.x * blockDim.x + threadIdx.x) >> 6;
  int lane = threadIdx.x & 63;
  if (wid >= Npad) return;
  float a0 = 0.f, a1 = 0.f;
  if (wid < N) {
    const int* xr = x + (size_t)wid * FEAT;
#pragma unroll
    for (int f = 0; f < FEAT; ++f) {
      int id = xr[f];
      const float* e = emb + ((size_t)f * maxv + id) * H;
      a0 += e[lane];
      a1 += e[lane + 64];
    }
  }
  h[(size_t)wid * H + lane] = a0;
  h[(size_t)wid * H + 64 + lane] = a1;
}

// ---------------- degree count (by dst) ----------------
__global__ __launch_bounds__(256) void k_count(const int* __restrict__ dst,
    int* __restrict__ counts, int E) {
  int i = blockIdx.x * blockDim.x + threadIdx.x;
  if (i < E) atomicAdd(&counts[dst[i]], 1);
}

// ---------------- dinv = rsqrt(deg), deg = in_count + 1 (self loop) ----------------
__global__ __launch_bounds__(256) void k_dinv(const int* __restrict__ counts,
    float* __restrict__ dinv, int N) {
  int i = blockIdx.x * blockDim.x + threadIdx.x;
  if (i < N) dinv[i] = rsqrtf((float)(counts[i] + 1));
}

// ---------------- exclusive scan: row_ptr[0]=0, row_ptr[i+1]=sum counts[0..i] ----------------
__global__ __launch_bounds__(1024) void k_scan(const int* __restrict__ counts,
    int* __restrict__ row_ptr, int n) {
  __shared__ int buf[1024];
  __shared__ int carry;
  int t = threadIdx.x;
  if (t == 0) { carry = 0; row_ptr[0] = 0; }
  __syncthreads();
  for (int base = 0; base < n; base += 1024) {
    int i = base + t;
    int v = (i < n) ? counts[i] : 0;
    buf[t] = v;
    __syncthreads();
    for (int off = 1; off < 1024; off <<= 1) {
      int xv = (t >= off) ? buf[t - off] : 0;
      __syncthreads();
      buf[t] += xv;
      __syncthreads();
    }
    if (i < n) row_ptr[i + 1] = carry + buf[t];
    __syncthreads();
    if (t == 1023) carry += buf[1023];
    __syncthreads();
  }
}

// ---------------- CSR fill: col[row_ptr[dst]+k] = src ----------------
__global__ __launch_bounds__(256) void k_fill(const int* __restrict__ src,
    const int* __restrict__ dst, const int* __restrict__ row_ptr,
    int* __restrict__ cursor, int* __restrict__ col, int E) {
  int i = blockIdx.x * blockDim.x + threadIdx.x;
  if (i < E) {
    int d = dst[i];
    int pos = atomicAdd(&cursor[d], 1);
    col[row_ptr[d] + pos] = src[i];
  }
}

// ---------------- fp32 GEMM: C[Npad x 128] = A[Npad x 128] @ W[128 x 128] ----------------
__global__ __launch_bounds__(256) void k_gemm(const float* __restrict__ A,
    const float* __restrict__ W, float* __restrict__ C, int Npad) {
  __shared__ float sA[64][65];   // padded, scalar-accessed
  __shared__ float sB[64][128];
  int t = threadIdx.x;
  int row0 = blockIdx.x * 64;
  int tr = (t & 15) << 2;        // 4 rows
  int tc = (t >> 4) << 3;        // 8 cols
  float acc[4][8];
#pragma unroll
  for (int i = 0; i < 4; ++i)
#pragma unroll
    for (int j = 0; j < 8; ++j) acc[i][j] = 0.f;

  for (int kt = 0; kt < 2; ++kt) {
    // stage A tile 64x64
#pragma unroll
    for (int i = 0; i < 4; ++i) {
      int fi = t + i * 256;          // float4 units, 16 per row
      int r = fi >> 4;
      int kk = (fi & 15) << 2;
      float4 v = *(const float4*)(A + (size_t)(row0 + r) * H + kt * 64 + kk);
      sA[r][kk + 0] = v.x; sA[r][kk + 1] = v.y;
      sA[r][kk + 2] = v.z; sA[r][kk + 3] = v.w;
    }
    // stage W tile 64x128
#pragma unroll
    for (int i = 0; i < 8; ++i) {
      int fi = t + i * 256;          // float4 units, 32 per row
      int k = fi >> 5;
      int nn = (fi & 31) << 2;
      *(float4*)&sB[k][nn] = *(const float4*)(W + (size_t)(kt * 64 + k) * H + nn);
    }
    __syncthreads();
#pragma unroll 8
    for (int k = 0; k < 64; ++k) {
      float a0 = sA[tr + 0][k], a1 = sA[tr + 1][k];
      float a2 = sA[tr + 2][k], a3 = sA[tr + 3][k];
      float4 b0 = *(float4*)&sB[k][tc];
      float4 b1 = *(float4*)&sB[k][tc + 4];
      float bj[8] = {b0.x, b0.y, b0.z, b0.w, b1.x, b1.y, b1.z, b1.w};
#pragma unroll
      for (int j = 0; j < 8; ++j) {
        acc[0][j] += a0 * bj[j];
        acc[1][j] += a1 * bj[j];
        acc[2][j] += a2 * bj[j];
        acc[3][j] += a3 * bj[j];
      }
    }
    __syncthreads();
  }
#pragma unroll
  for (int i = 0; i < 4; ++i) {
    float4 o0 = {acc[i][0], acc[i][1], acc[i][2], acc[i][3]};
    float4 o1 = {acc[i][4], acc[i][5], acc[i][6], acc[i][7]};
    *(float4*)(C + (size_t)(row0 + tr + i) * H + tc) = o0;
    *(float4*)(C + (size_t)(row0 + tr + i) * H + tc + 4) = o1;
  }
}

// ---------------- aggregate + bias + relu + BN partial stats ----------------
__global__ __launch_bounds__(256) void k_agg(const float* __restrict__ m,
    const int* __restrict__ row_ptr, const int* __restrict__ col,
    const float* __restrict__ dinv, const float* __restrict__ bias,
    float* __restrict__ a, float* __restrict__ bn_sum, float* __restrict__ bn_sq,
    int N) {
  __shared__ float s_sum[128], s_sq[128];
  for (int i = threadIdx.x; i < 128; i += blockDim.x) { s_sum[i] = 0.f; s_sq[i] = 0.f; }
  __syncthreads();
  int lane = threadIdx.x & 63;
  int wid = (blockIdx.x * blockDim.x + threadIdx.x) >> 6;
  int nw = (gridDim.x * blockDim.x) >> 6;
  float b0 = bias[lane], b1 = bias[64 + lane];
  float lsum0 = 0.f, lsq0 = 0.f, lsum1 = 0.f, lsq1 = 0.f;
  for (int v = wid; v < N; v += nw) {
    int s0 = row_ptr[v], s1 = row_ptr[v + 1];
    float dv = dinv[v];
    float acc0 = dv * m[(size_t)v * H + lane];
    float acc1 = dv * m[(size_t)v * H + 64 + lane];
    for (int s = s0; s < s1; ++s) {
      int u = col[s];
      float w = dinv[u];
      acc0 += w * m[(size_t)u * H + lane];
      acc1 += w * m[(size_t)u * H + 64 + lane];
    }
    float a0 = fmaxf(dv * acc0 + b0, 0.f);
    float a1 = fmaxf(dv * acc1 + b1, 0.f);
    a[(size_t)v * H + lane] = a0;
    a[(size_t)v * H + 64 + lane] = a1;
    lsum0 += a0; lsq0 += a0 * a0;
    lsum1 += a1; lsq1 += a1 * a1;
  }
  atomicAdd(&s_sum[lane], lsum0);
  atomicAdd(&s_sum[64 + lane], lsum1);
  atomicAdd(&s_sq[lane], lsq0);
  atomicAdd(&s_sq[64 + lane], lsq1);
  __syncthreads();
  for (int i = threadIdx.x; i < 128; i += blockDim.x) {
    atomicAdd(&bn_sum[i], s_sum[i]);
    atomicAdd(&bn_sq[i], s_sq[i]);
  }
}

// ---------------- BN finalize + relu + residual (in-place h) ----------------
__global__ __launch_bounds__(256) void k_bn(const float* __restrict__ a,
    float* __restrict__ h, const float* __restrict__ bn_sum,
    const float* __restrict__ bn_sq, const float* __restrict__ gamma,
    const float* __restrict__ beta, int N) {
  int idx = blockIdx.x * blockDim.x + threadIdx.x;   // float4 index over N*32
  int total = N * 32;
  if (idx >= total) return;
  int c4 = idx & 31;
  float invN = 1.0f / (float)N;
  float4 s = *(const float4*)(bn_sum + c4 * 4);
  float4 q = *(const float4*)(bn_sq + c4 * 4);
  float4 g = *(const float4*)(gamma + c4 * 4);
  float4 be = *(const float4*)(beta + c4 * 4);
  float4 av = *(const float4*)(a + (size_t)idx * 4);
  float4 hv = *(const float4*)(h + (size_t)idx * 4);
  float4 o;
  {
    float mean = s.x * invN; float var = q.x * invN - mean * mean;
    float sc = g.x * rsqrtf(var + 1e-5f);
    o.x = fmaxf(sc * (av.x - mean) + be.x, 0.f) + hv.x;
  }
  {
    float mean = s.y * invN; float var = q.y * invN - mean * mean;
    float sc = g.y * rsqrtf(var + 1e-5f);
    o.y = fmaxf(sc * (av.y - mean) + be.y, 0.f) + hv.y;
  }
  {
    float mean = s.z * invN; float var = q.z * invN - mean * mean;
    float sc = g.z * rsqrtf(var + 1e-5f);
    o.z = fmaxf(sc * (av.z - mean) + be.z, 0.f) + hv.z;
  }
  {
    float mean = s.w * invN; float var = q.w * invN - mean * mean;
    float sc = g.w * rsqrtf(var + 1e-5f);
    o.w = fmaxf(sc * (av.w - mean) + be.w, 0.f) + hv.w;
  }
  *(float4*)(h + (size_t)idx * 4) = o;
}

// ---------------- mean-pool readout (atomic) ----------------
__global__ __launch_bounds__(256) void k_pool(const float* __restrict__ h,
    const int* __restrict__ batch, float* __restrict__ pooled,
    float* __restrict__ gcnt, int N) {
  int wid = (blockIdx.x * blockDim.x + threadIdx.x) >> 6;
  int lane = threadIdx.x & 63;
  if (wid >= N) return;
  int g = batch[wid];
  atomicAdd(&pooled[(size_t)g * H + lane], h[(size_t)wid * H + lane]);
  atomicAdd(&pooled[(size_t)g * H + 64 + lane], h[(size_t)wid * H + 64 + lane]);
  if (lane == 0) atomicAdd(&gcnt[g], 1.0f);
}

// ---------------- final: sigmoid(pooled/cnt @ lin_W + lin_b) ----------------
__global__ __launch_bounds__(256) void k_out(const float* __restrict__ pooled,
    const float* __restrict__ gcnt, const float* __restrict__ lw,
    const float* __restrict__ lb, float* __restrict__ out, int G) {
  int wid = (blockIdx.x * blockDim.x + threadIdx.x) >> 6;
  int lane = threadIdx.x & 63;
  if (wid >= G) return;
  float inv = 1.f / fmaxf(gcnt[wid], 1.f);
  float s = pooled[(size_t)wid * H + lane] * inv * lw[lane]
          + pooled[(size_t)wid * H + 64 + lane] * inv * lw[64 + lane];
#pragma unroll
  for (int off = 32; off > 0; off >>= 1) s += __shfl_down(s, off, 64);
  if (lane == 0) out[wid] = 1.f / (1.f + expf(-(s + lb[0])));
}

extern "C" void kernel_launch(void* const* d_in, const int* in_sizes, int n_in,
                              void* d_out, int out_size, void* d_ws, size_t ws_size,
                              hipStream_t stream) {
  const int* x      = (const int*)d_in[0];
  const int* ei     = (const int*)d_in[1];
  const int* batch  = (const int*)d_in[2];
  const float* emb  = (const float*)d_in[3];
  const float* convW = (const float*)d_in[4];
  const float* convB = (const float*)d_in[5];
  const float* gamma = (const float*)d_in[6];
  const float* beta  = (const float*)d_in[7];
  const float* lw    = (const float*)d_in[8];
  const float* lb    = (const float*)d_in[9];
  float* out = (float*)d_out;

  const int N = in_sizes[2];
  const int E = in_sizes[1] / 2;
  const int G = out_size;
  const int MAXV = in_sizes[3] / (FEAT * H);
  const int L = in_sizes[4] / (H * H);
  const int Npad = (N + 63) & ~63;

  const int* srcp = ei;
  const int* dstp = ei + E;

  // workspace carve-up (assume d_ws 256B aligned)
  char* p = (char*)d_ws;
  auto alloc = [&](size_t bytes) { char* r = p; p += (bytes + 255) & ~255ull; return r; };
  float* h    = (float*)alloc((size_t)Npad * H * 4);
  float* m    = (float*)alloc((size_t)Npad * H * 4);
  float* a    = (float*)alloc((size_t)Npad * H * 4);
  float* dinv = (float*)alloc((size_t)N * 4);
  int* row_ptr = (int*)alloc((size_t)(N + 1) * 4);
  int* col     = (int*)alloc((size_t)E * 4);
  char* z0 = p;
  int* counts   = (int*)alloc((size_t)N * 4);
  int* cursor   = (int*)alloc((size_t)N * 4);
  float* bn_sum = (float*)alloc((size_t)L * H * 4);
  float* bn_sq  = (float*)alloc((size_t)L * H * 4);
  float* pooled = (float*)alloc((size_t)G * H * 4);
  float* gcnt   = (float*)alloc((size_t)G * 4);
  size_t zbytes = (size_t)(p - z0);

  hipMemsetAsync(z0, 0, zbytes, stream);

  // graph prep
  k_atom<<<Npad / 4, 256, 0, stream>>>(x, emb, h, N, Npad, MAXV);
  k_count<<<(E + 255) / 256, 256, 0, stream>>>(dstp, counts, E);
  k_dinv<<<(N + 255) / 256, 256, 0, stream>>>(counts, dinv, N);
  k_scan<<<1, 1024, 0, stream>>>(counts, row_ptr, N);
  k_fill<<<(E + 255) / 256, 256, 0, stream>>>(srcp, dstp, row_ptr, cursor, col, E);

  // layers
  for (int l = 0; l < L; ++l) {
    k_gemm<<<Npad / 64, 256, 0, stream>>>(h, convW + (size_t)l * H * H, m, Npad);
    k_agg<<<2048, 256, 0, stream>>>(m, row_ptr, col, dinv, convB + (size_t)l * H,
                                    a, bn_sum + (size_t)l * H, bn_sq + (size_t)l * H, N);
    k_bn<<<(N * 32 + 255) / 256, 256, 0, stream>>>(a, h, bn_sum + (size_t)l * H,
                                                   bn_sq + (size_t)l * H,
                                                   gamma + (size_t)l * H,
                                                   beta + (size_t)l * H, N);
  }

  // readout
  k_pool<<<(N + 3) / 4, 256, 0, stream>>>(h, batch, pooled, gcnt, N);
  k_out<<<(G + 3) / 4, 256, 0, stream>>>(pooled, gcnt, lw, lb, out, G);
}